// Round 1
// baseline (237.899 us; speedup 1.0000x reference)
//
#include <hip/hip_runtime.h>
#include <hip/hip_bf16.h>
#include <cstdint>

#define N_ATOMS 100000
#define NFEAT   256
#define NMOL    1024
#define NU      6256    // 100096 / 16 atoms per unit

static constexpr float SCALE_C = 5.992277830325989f;
static constexpr float SHIFT_C = -406274.63784969115f;

typedef __attribute__((ext_vector_type(8))) short short8;    // bf16x8 MFMA operand
typedef __attribute__((ext_vector_type(4))) float float4_t;  // f32x4 accumulator

__device__ __forceinline__ unsigned short f2bf(float x) {
    union { float f; uint32_t u; } v; v.f = x;
    uint32_t r = (v.u + 0x7fffu + ((v.u >> 16) & 1u)) >> 16;
    return (unsigned short)r;
}

// pack two fp32 -> two bf16 (round-half-up) in one v_perm
__device__ __forceinline__ uint32_t pk(float lo, float hi) {
    union { float f; uint32_t u; } a, b; a.f = lo; b.f = hi;
    return __builtin_amdgcn_perm(b.u + 0x8000u, a.u + 0x8000u, 0x07060302u);
}

__device__ __forceinline__ float silu(float x) {
    return x / (1.0f + __expf(-x));
}

// async global->LDS, 16B/lane; LDS dest wave-uniform, lane i lands at +i*16B
__device__ __forceinline__ void async16(void* lds, const void* g) {
    __builtin_amdgcn_global_load_lds(
        (const __attribute__((address_space(1))) unsigned int*)(uintptr_t)g,
        (__attribute__((address_space(3))) unsigned int*)(uint32_t)(uintptr_t)lds,
        16, 0, 0);
}

// Full 256x256 W image in LDS (R4-verified layout, 0 bank conflicts):
//   pos = (kc>>4)*32768 + n*128 + (((kc&15) ^ (n&15))<<3)  [+ (k&7)]
__device__ __forceinline__ short8 wfrag(const unsigned short* Wlds, int n, int kc) {
    return *(const short8*)&Wlds[((kc >> 4) << 15) + n * 128 +
                                 ((((kc & 15) ^ (n & 15)) & 15) << 3)];
}

// ---------------------------------------------------------------------------
// Prep: W1,W2 fp32 [k][n] -> bf16 swizzled plane images; init out[] = SHIFT.
// ---------------------------------------------------------------------------
__global__ void prep(const float* __restrict__ W1, const float* __restrict__ W2,
                     unsigned short* __restrict__ W1i, unsigned short* __restrict__ W2i,
                     float* __restrict__ out) {
    int g = blockIdx.x * 256 + threadIdx.x;          // 0 .. 131071
    const float* W = (g < 65536) ? W1 : W2;
    unsigned short* Wi = (g < 65536) ? W1i : W2i;
    int idx = g & 65535;
    int k = idx >> 8, n = idx & 255;
    int kc = (k >> 3) & 15;
    int pos = ((k >> 7) << 15) + n * 128 + (((kc ^ (n & 15)) & 15) << 3) + (k & 7);
    Wi[pos] = f2bf(W[idx]);
    if (g < NMOL) out[g] = SHIFT_C;
}

// ---------------------------------------------------------------------------
// Layer 1: H1 = silu(A @ W1 + b1). 1024 thr = 16 waves (4/SIMD), 1 block/CU;
// full W1 (128 KB) staged to LDS once, ONE barrier total. R8: was 512 thr /
// 8 waves -> latency-bound (MfmaUtil 7.4%, VALU 22%, HBM 20%, all idle at
// once); doubling waves doubles latency hiding; VGPR 88 fits the 128-reg
// cap for 4 waves/EU. Waves stream 16-atom x 256-col units via per-block
// LDS steal counter; A loads prefetched one k-step ahead (depth-2 pipeline).
// acc[16]=64 regs -> no spill. Swapped MFMA operands: lane fl owns atom
// u*16+fl, cols j*16+qd*4+r -> uint2 stores.
// ---------------------------------------------------------------------------
__global__ __launch_bounds__(1024, 4)
void gemm1(const float* __restrict__ A, const unsigned short* __restrict__ Wimg,
           const float* __restrict__ b1, unsigned short* __restrict__ H1) {
    __shared__ unsigned short Wlds[65536];   // 128 KB
    __shared__ float b1L[256];
    __shared__ int uctr;

    const int tid = threadIdx.x;
    const int w = tid >> 6, lane = tid & 63;
    const int fl = lane & 15, qd = lane >> 4;

#pragma unroll
    for (int i = 0; i < 8; ++i)
        async16(&Wlds[(w * 8 + i) * 512], Wimg + (w * 8 + i) * 512 + lane * 8);
    if (tid < 64) ((float4*)b1L)[tid] = ((const float4*)b1)[tid];
    if (tid == 0) uctr = 0;
    __syncthreads();

    for (;;) {
        int t = 0;
        if (lane == 0) t = atomicAdd(&uctr, 1);   // LDS atomic
        t = __shfl(t, 0);
        const int u = blockIdx.x + (t << 8);      // stride-256 across blocks
        if (u >= NU) break;

        const int row = u * 16 + fl;              // this lane's atom
        const bool valid = row < N_ATOMS;
        const float* ap = A + (size_t)row * 256 + qd * 8;

        float4 c0, c1;
        if (valid) { c0 = *(const float4*)ap; c1 = *(const float4*)(ap + 4); }
        else       { c0 = make_float4(0, 0, 0, 0); c1 = c0; }

        float4_t acc[16] = {};
#pragma unroll
        for (int s = 0; s < 8; ++s) {
            float4 n0 = make_float4(0, 0, 0, 0), n1 = n0;
            if (s < 7 && valid) {                  // prefetch next k-step
                n0 = *(const float4*)(ap + (s + 1) * 32);
                n1 = *(const float4*)(ap + (s + 1) * 32 + 4);
            }
            union { uint32_t u4[4]; short8 s8; } cv;
            cv.u4[0] = pk(c0.x, c0.y); cv.u4[1] = pk(c0.z, c0.w);
            cv.u4[2] = pk(c1.x, c1.y); cv.u4[3] = pk(c1.z, c1.w);
            const int kc = s * 4 + qd;
#pragma unroll
            for (int j = 0; j < 16; ++j) {
                short8 wf = wfrag(Wlds, j * 16 + fl, kc);
                acc[j] = __builtin_amdgcn_mfma_f32_16x16x32_bf16(wf, cv.s8, acc[j], 0, 0, 0);
            }
            c0 = n0; c1 = n1;
        }

        if (valid) {
#pragma unroll
            for (int j = 0; j < 16; ++j) {
                int nb = j * 16 + qd * 4;
                float4 b4 = *(const float4*)&b1L[nb];
                uint2 o;
                o.x = pk(silu(acc[j][0] + b4.x), silu(acc[j][1] + b4.y));
                o.y = pk(silu(acc[j][2] + b4.z), silu(acc[j][3] + b4.w));
                *(uint2*)&H1[(size_t)row * 256 + nb] = o;
            }
        }
    }
}

// ---------------------------------------------------------------------------
// Layer 2+3+pool: out[mol] += SCALE*(silu(H1@W2+b2).W3 + b3). Same streaming
// structure (16 waves, R8), natural operand order; unit covers ALL 256 cols
// so b3 is added once per atom. Pooling via LDS bucket[1024] (R7-verified),
// one global atomic per nonzero bucket at the end.
// ---------------------------------------------------------------------------
__global__ __launch_bounds__(1024, 4)
void gemm2(const unsigned short* __restrict__ H1, const unsigned short* __restrict__ Wimg,
           const float* __restrict__ b2, const float* __restrict__ W3,
           const float* __restrict__ b3, const int* __restrict__ batch,
           float* __restrict__ out) {
    __shared__ unsigned short Wlds[65536];   // 128 KB
    __shared__ float bucket[NMOL];           // 4 KB
    __shared__ int uctr;

    const int tid = threadIdx.x;
    const int w = tid >> 6, lane = tid & 63;
    const int fl = lane & 15, qd = lane >> 4;

#pragma unroll
    for (int i = 0; i < 8; ++i)
        async16(&Wlds[(w * 8 + i) * 512], Wimg + (w * 8 + i) * 512 + lane * 8);
    bucket[tid] = 0.0f;
    if (tid == 0) uctr = 0;
    __syncthreads();

    const float b3v = b3[0];
    float bbv[16], w3v[16];
#pragma unroll
    for (int nt = 0; nt < 16; ++nt) {
        bbv[nt] = b2[nt * 16 + fl];
        w3v[nt] = W3[nt * 16 + fl];
    }

    for (;;) {
        int t = 0;
        if (lane == 0) t = atomicAdd(&uctr, 1);
        t = __shfl(t, 0);
        const int u = blockIdx.x + (t << 8);
        if (u >= NU) break;

        const int ubase = u * 16;
        const int row = ubase + fl;
        const bool valid = row < N_ATOMS;
        const unsigned short* hp = H1 + (size_t)row * 256 + qd * 8;

        short8 h0 = (short8){0, 0, 0, 0, 0, 0, 0, 0};
        if (valid) h0 = *(const short8*)hp;

        float4_t acc[16] = {};
#pragma unroll
        for (int s = 0; s < 8; ++s) {
            short8 hn = (short8){0, 0, 0, 0, 0, 0, 0, 0};
            if (s < 7 && valid) hn = *(const short8*)(hp + (s + 1) * 32);
            const int kc = s * 4 + qd;
#pragma unroll
            for (int nt = 0; nt < 16; ++nt) {
                short8 wf = wfrag(Wlds, nt * 16 + fl, kc);
                acc[nt] = __builtin_amdgcn_mfma_f32_16x16x32_bf16(h0, wf, acc[nt], 0, 0, 0);
            }
            h0 = hn;
        }

        // acc[nt][r]: atom = ubase + qd*4 + r, col = nt*16 + fl
        float rs[4] = {};
#pragma unroll
        for (int nt = 0; nt < 16; ++nt)
#pragma unroll
            for (int r = 0; r < 4; ++r)
                rs[r] += silu(acc[nt][r] + bbv[nt]) * w3v[nt];
#pragma unroll
        for (int r = 0; r < 4; ++r) {
            float v = rs[r];
            v += __shfl_xor(v, 1);
            v += __shfl_xor(v, 2);
            v += __shfl_xor(v, 4);
            v += __shfl_xor(v, 8);
            rs[r] = v;
        }
        if (fl == 0) {
            int atom0 = ubase + qd * 4;
            if (atom0 < N_ATOMS) {   // atom0 % 4 == 0 -> all 4 rows valid
                int4 mb = *(const int4*)&batch[atom0];
                float v0 = rs[0] + b3v, v1 = rs[1] + b3v,
                      v2 = rs[2] + b3v, v3 = rs[3] + b3v;
                if (mb.x == mb.w) {
                    atomicAdd(&bucket[mb.x], (v0 + v1) + (v2 + v3));
                } else {
                    atomicAdd(&bucket[mb.x], v0);
                    atomicAdd(&bucket[mb.y], v1);
                    atomicAdd(&bucket[mb.z], v2);
                    atomicAdd(&bucket[mb.w], v3);
                }
            }
        }
    }
    __syncthreads();
    {
        float v = bucket[tid];
        if (v != 0.0f) atomicAdd(&out[tid], v * SCALE_C);
    }
}

// ---------------------------------------------------------------------------
extern "C" void kernel_launch(void* const* d_in, const int* in_sizes, int n_in,
                              void* d_out, int out_size, void* d_ws, size_t ws_size,
                              hipStream_t stream) {
    const float* A     = (const float*)d_in[0];
    const int*   batch = (const int*)d_in[1];
    const float* W1    = (const float*)d_in[2];
    const float* b1    = (const float*)d_in[3];
    const float* W2    = (const float*)d_in[4];
    const float* b2    = (const float*)d_in[5];
    const float* W3    = (const float*)d_in[6];
    const float* b3    = (const float*)d_in[7];
    float* out = (float*)d_out;

    unsigned short* H1  = (unsigned short*)d_ws;            // 100096*256 bf16
    unsigned short* W1i = H1 + (size_t)100096 * NFEAT;      // 65536 shorts
    unsigned short* W2i = W1i + 65536;                      // 65536 shorts

    prep<<<dim3(512), 256, 0, stream>>>(W1, W2, W1i, W2i, out);
    gemm1<<<dim3(256), 1024, 0, stream>>>(A, W1i, b1, H1);
    gemm2<<<dim3(256), 1024, 0, stream>>>(H1, W2i, b2, W3, b3, batch, out);
}